// Round 3
// baseline (126.751 us; speedup 1.0000x reference)
//
#include <hip/hip_runtime.h>
#include <math.h>

#define DD 256
#define NTHREADS 256
#define UNR 4   // 4 float4 loads in flight per thread per batch (16 rows/block/iter)

typedef float fvec4 __attribute__((ext_vector_type(4)));

__global__ __launch_bounds__(NTHREADS) void dxent_kernel(
    const float* __restrict__ m,
    const float* __restrict__ k,
    const int* __restrict__ idx,
    float* __restrict__ out)
{
    const int b = blockIdx.x;
    const int t = threadIdx.x;
    const int lane = t & 63;
    const int wave = t >> 6;

    const float* mrow = m + (size_t)b * DD;
    const float* kmat = k + (size_t)b * DD * DD;

    __shared__ float p_s[DD];
    __shared__ float red_s[8];

    const int cg = lane * 4;   // this lane's column group

    // ---- prefetch batch 0 of k (rows wave, wave+4, wave+8, wave+12) ----
    // Independent of softmax; hides the softmax barriers under HBM latency.
    fvec4 v0[UNR];
    #pragma unroll
    for (int u = 0; u < UNR; ++u) {
        const int r = 4 * u + wave;
        v0[u] = __builtin_nontemporal_load(
            reinterpret_cast<const fvec4*>(&kmat[(size_t)r * DD + cg]));
    }

    // ---- softmax over m[b, :] (one element per thread) ----
    float mv = mrow[t];

    float x = mv;
    #pragma unroll
    for (int off = 32; off >= 1; off >>= 1)
        x = fmaxf(x, __shfl_xor(x, off));
    if (lane == 0) red_s[wave] = x;
    __syncthreads();
    float rowmax = fmaxf(fmaxf(red_s[0], red_s[1]), fmaxf(red_s[2], red_s[3]));

    float e = expf(mv - rowmax);
    float s = e;
    #pragma unroll
    for (int off = 32; off >= 1; off >>= 1)
        s += __shfl_xor(s, off);
    if (lane == 0) red_s[4 + wave] = s;
    __syncthreads();
    float sum = red_s[4] + red_s[5] + red_s[6] + red_s[7];
    float pj = e * (1.0f / sum);
    p_s[t] = pj;
    __syncthreads();

    // ---- contraction: wave w owns rows r ≡ w (mod 4); lane l owns cols 4l..4l+3 ----
    fvec4 qacc = (fvec4)(0.f);
    float tacc = 0.f;

    // consume one batch of UNR row-groups starting at rb, with loads already in v[]
    auto consume = [&](const fvec4* v, int rb) {
        float pr[UNR];
        #pragma unroll
        for (int u = 0; u < UNR; ++u) pr[u] = p_s[rb + 4 * u + wave];
        #pragma unroll
        for (int u = 0; u < UNR; ++u) {
            qacc.x = fmaf(v[u].x, pr[u], qacc.x);
            qacc.y = fmaf(v[u].y, pr[u], qacc.y);
            qacc.z = fmaf(v[u].z, pr[u], qacc.z);
            qacc.w = fmaf(v[u].w, pr[u], qacc.w);
            const int d = rb + 4 * u + wave - cg;
            if ((unsigned)d < 4u) {   // diagonal element k[r,r] lives in this float4
                const float dv = (d == 0) ? v[u].x : (d == 1) ? v[u].y
                               : (d == 2) ? v[u].z : v[u].w;
                tacc = fmaf(dv, pr[u], tacc);
            }
        }
    };

    consume(v0, 0);

    for (int rb = 4 * UNR; rb < DD; rb += 4 * UNR) {
        fvec4 v[UNR];
        #pragma unroll
        for (int u = 0; u < UNR; ++u) {
            const int r = rb + 4 * u + wave;
            v[u] = __builtin_nontemporal_load(
                reinterpret_cast<const fvec4*>(&kmat[(size_t)r * DD + cg]));
        }
        consume(v, rb);
    }

    // ---- reductions: quad = p^T K p, trace = sum diag(K)*p ----
    const float4 pc = *reinterpret_cast<const float4*>(&p_s[cg]);
    float q = qacc.x * pc.x + qacc.y * pc.y + qacc.z * pc.z + qacc.w * pc.w;
    float tr = tacc;

    #pragma unroll
    for (int off = 32; off >= 1; off >>= 1) {
        q  += __shfl_xor(q, off);
        tr += __shfl_xor(tr, off);
    }
    __syncthreads();
    if (lane == 0) { red_s[wave] = q; red_s[4 + wave] = tr; }
    __syncthreads();

    if (t == 0) {
        const float qt = red_s[0] + red_s[1] + red_s[2] + red_s[3];
        const float tt = red_s[4] + red_s[5] + red_s[6] + red_s[7];
        const float lse = rowmax + logf(sum);
        const float picked = mrow[idx[b]];
        out[b] = lse - picked + 0.5f * (tt - qt);
    }
}

extern "C" void kernel_launch(void* const* d_in, const int* in_sizes, int n_in,
                              void* d_out, int out_size, void* d_ws, size_t ws_size,
                              hipStream_t stream) {
    const float* m = (const float*)d_in[0];
    const float* k = (const float*)d_in[1];
    const int* idx = (const int*)d_in[2];
    float* out = (float*)d_out;

    const int B = out_size;   // 2048
    dxent_kernel<<<B, NTHREADS, 0, stream>>>(m, k, idx, out);
}

// Round 4
// 99.397 us; speedup vs baseline: 1.2752x; 1.2752x over previous
//
#include <hip/hip_runtime.h>
#include <math.h>

#define DD 256
#define NTHREADS 256
#define UNR 4   // 4 float4 loads in flight per thread per batch (16 rows/block/iter)

__global__ __launch_bounds__(NTHREADS) void dxent_kernel(
    const float* __restrict__ m,
    const float* __restrict__ k,
    const int* __restrict__ idx,
    float* __restrict__ out)
{
    const int b = blockIdx.x;
    const int t = threadIdx.x;
    const int lane = t & 63;
    const int wave = t >> 6;

    const float* mrow = m + (size_t)b * DD;
    const float* kmat = k + (size_t)b * DD * DD;

    __shared__ float p_s[DD];
    __shared__ float red_s[8];

    const int cg = lane * 4;   // this lane's column group

    // ---- prefetch batch 0 of k (rows wave, wave+4, wave+8, wave+12) ----
    // Independent of softmax; hides the softmax barriers under HBM latency.
    float4 v0[UNR];
    #pragma unroll
    for (int u = 0; u < UNR; ++u) {
        const int r = 4 * u + wave;
        v0[u] = *reinterpret_cast<const float4*>(&kmat[(size_t)r * DD + cg]);
    }

    // ---- softmax over m[b, :] (one element per thread) ----
    float mv = mrow[t];

    float x = mv;
    #pragma unroll
    for (int off = 32; off >= 1; off >>= 1)
        x = fmaxf(x, __shfl_xor(x, off));
    if (lane == 0) red_s[wave] = x;
    __syncthreads();
    float rowmax = fmaxf(fmaxf(red_s[0], red_s[1]), fmaxf(red_s[2], red_s[3]));

    float e = expf(mv - rowmax);
    float s = e;
    #pragma unroll
    for (int off = 32; off >= 1; off >>= 1)
        s += __shfl_xor(s, off);
    if (lane == 0) red_s[4 + wave] = s;
    __syncthreads();
    float sum = red_s[4] + red_s[5] + red_s[6] + red_s[7];
    float pj = e * (1.0f / sum);
    p_s[t] = pj;
    __syncthreads();

    // ---- contraction: wave w owns rows r ≡ w (mod 4); lane l owns cols 4l..4l+3 ----
    float4 qacc = make_float4(0.f, 0.f, 0.f, 0.f);
    float tacc = 0.f;

    // consume one batch of UNR row-groups starting at rb, with loads already in v[]
    auto consume = [&](const float4* v, int rb) {
        float pr[UNR];
        #pragma unroll
        for (int u = 0; u < UNR; ++u) pr[u] = p_s[rb + 4 * u + wave];
        #pragma unroll
        for (int u = 0; u < UNR; ++u) {
            qacc.x = fmaf(v[u].x, pr[u], qacc.x);
            qacc.y = fmaf(v[u].y, pr[u], qacc.y);
            qacc.z = fmaf(v[u].z, pr[u], qacc.z);
            qacc.w = fmaf(v[u].w, pr[u], qacc.w);
            const int d = rb + 4 * u + wave - cg;
            if ((unsigned)d < 4u) {   // diagonal element k[r,r] lives in this float4
                const float dv = (d == 0) ? v[u].x : (d == 1) ? v[u].y
                               : (d == 2) ? v[u].z : v[u].w;
                tacc = fmaf(dv, pr[u], tacc);
            }
        }
    };

    consume(v0, 0);

    for (int rb = 4 * UNR; rb < DD; rb += 4 * UNR) {
        float4 v[UNR];
        #pragma unroll
        for (int u = 0; u < UNR; ++u) {
            const int r = rb + 4 * u + wave;
            v[u] = *reinterpret_cast<const float4*>(&kmat[(size_t)r * DD + cg]);
        }
        consume(v, rb);
    }

    // ---- reductions: quad = p^T K p, trace = sum diag(K)*p ----
    const float4 pc = *reinterpret_cast<const float4*>(&p_s[cg]);
    float q = qacc.x * pc.x + qacc.y * pc.y + qacc.z * pc.z + qacc.w * pc.w;
    float tr = tacc;

    #pragma unroll
    for (int off = 32; off >= 1; off >>= 1) {
        q  += __shfl_xor(q, off);
        tr += __shfl_xor(tr, off);
    }
    __syncthreads();
    if (lane == 0) { red_s[wave] = q; red_s[4 + wave] = tr; }
    __syncthreads();

    if (t == 0) {
        const float qt = red_s[0] + red_s[1] + red_s[2] + red_s[3];
        const float tt = red_s[4] + red_s[5] + red_s[6] + red_s[7];
        const float lse = rowmax + logf(sum);
        const float picked = mrow[idx[b]];
        out[b] = lse - picked + 0.5f * (tt - qt);
    }
}

extern "C" void kernel_launch(void* const* d_in, const int* in_sizes, int n_in,
                              void* d_out, int out_size, void* d_ws, size_t ws_size,
                              hipStream_t stream) {
    const float* m = (const float*)d_in[0];
    const float* k = (const float*)d_in[1];
    const int* idx = (const int*)d_in[2];
    float* out = (float*)d_out;

    const int B = out_size;   // 2048
    dxent_kernel<<<B, NTHREADS, 0, stream>>>(m, k, idx, out);
}